// Round 5
// baseline (225.363 us; speedup 1.0000x reference)
//
#include <hip/hip_runtime.h>

// Batched tiny GRU: B=512, T=4096, C=hidden=4.
// R5: CHUNK=16/WARM=48, grid (4,256) x 64 thr = 1024 waves = 1 wave/SIMD,
// but each lane runs TWO independent chains (b, b+256) stage-interleaved
// -> 2x ILP per wave without extra redundant warmup steps (R4's extra waves
// added +33% steps for no wall-clock gain; this adds ILP at constant work).
// Activations: sigmoid/tanh via exp2 + PAIRED rcp (rcp(d0*d1) + 2 muls
// recovers both) -> 18 trans-ops/step instead of 24.
// 4-step double-buffered float4 prefetch per chain; runtime-bounded warm
// loop keeps the hot body ~2.4k instr (I-cache friendly).

#define TB 512
#define TT 4096
#define CHUNK 16
#define WARM 48
#define NCH (TT / CHUNK)  // 256
#define L2E 1.4426950408889634f

__device__ __forceinline__ float fexp2(float x) { return __builtin_amdgcn_exp2f(x); }
__device__ __forceinline__ float frcp(float x)  { return __builtin_amdgcn_rcpf(x); }

__device__ __forceinline__ float f4c(const float4& v, int s) {
  switch (s) { case 0: return v.x; case 1: return v.y; case 2: return v.z; default: return v.w; }
}

__global__ __launch_bounds__(64, 1) void gru_scan(
    const float* __restrict__ x, const float* __restrict__ wih,
    const float* __restrict__ whh, const float* __restrict__ bih,
    const float* __restrict__ bhh, float* __restrict__ out) {
  const int lane = threadIdx.x;
  const int ch = blockIdx.y;
  const int t0 = ch * CHUNK;
  const int tw = (t0 >= WARM) ? (t0 - WARM) : 0;
  const int nW4 = (t0 - tw) >> 2;  // warm 4-step groups: 0,4,8,12 (even)

  // Uniform weights/biases.
  float Wi[12][4], Wh[12][4], bg[8], bnx[4], bnh[4];
#pragma unroll
  for (int g = 0; g < 12; ++g)
#pragma unroll
    for (int c = 0; c < 4; ++c) {
      Wi[g][c] = wih[g * 4 + c];
      Wh[g][c] = whh[g * 4 + c];
    }
#pragma unroll
  for (int g = 0; g < 8; ++g) bg[g] = bih[g] + bhh[g];
#pragma unroll
  for (int j = 0; j < 4; ++j) { bnx[j] = bih[8 + j]; bnh[j] = bhh[8 + j]; }

  const int b0 = blockIdx.x * 64 + lane;  // [0,256)
  const float* px[2][4];
  float* po[2][4];
#pragma unroll
  for (int k = 0; k < 2; ++k)
#pragma unroll
    for (int c = 0; c < 4; ++c) {
      const size_t bb = (size_t)(b0 + 256 * k) * 4 + c;
      px[k][c] = x + bb * TT + tw;
      po[k][c] = out + bb * TT + t0;
    }

  float h[2][4] = {{0.f, 0.f, 0.f, 0.f}, {0.f, 0.f, 0.f, 0.f}};

  float4 XA[2][4], XB[2][4];

  auto LDA = [&](int off) {
#pragma unroll
    for (int k = 0; k < 2; ++k)
#pragma unroll
      for (int c = 0; c < 4; ++c) XA[k][c] = *(const float4*)(px[k][c] + off);
  };
  auto LDB = [&](int off) {
#pragma unroll
    for (int k = 0; k < 2; ++k)
#pragma unroll
      for (int c = 0; c < 4; ++c) XB[k][c] = *(const float4*)(px[k][c] + off);
  };

  // One GRU step for BOTH chains, stage-interleaved for ILP.
  auto STEPD = [&](const float (&xx)[2][4]) {
    float ar[2][8];
#pragma unroll
    for (int g = 0; g < 8; ++g)
#pragma unroll
      for (int k = 0; k < 2; ++k) {
        float s = fmaf(Wi[g][0], xx[k][0], bg[g]);
        s = fmaf(Wi[g][1], xx[k][1], s);
        s = fmaf(Wi[g][2], xx[k][2], s);
        s = fmaf(Wi[g][3], xx[k][3], s);
        s = fmaf(Wh[g][0], h[k][0], s);
        s = fmaf(Wh[g][1], h[k][1], s);
        s = fmaf(Wh[g][2], h[k][2], s);
        ar[k][g] = fmaf(Wh[g][3], h[k][3], s);
      }
    float sg[2][8];
#pragma unroll
    for (int p = 0; p < 4; ++p)
#pragma unroll
      for (int k = 0; k < 2; ++k) {
        float e0 = fexp2(ar[k][2 * p] * -L2E);
        float e1 = fexp2(ar[k][2 * p + 1] * -L2E);
        float d0 = 1.0f + e0, d1 = 1.0f + e1;
        float R = frcp(d0 * d1);  // one rcp serves both sigmoids
        sg[k][2 * p] = d1 * R;
        sg[k][2 * p + 1] = d0 * R;
      }
    float y[2][4];
#pragma unroll
    for (int j = 0; j < 4; ++j)
#pragma unroll
      for (int k = 0; k < 2; ++k) {
        float u = fmaf(Wi[8 + j][0], xx[k][0], bnx[j]);
        u = fmaf(Wi[8 + j][1], xx[k][1], u);
        u = fmaf(Wi[8 + j][2], xx[k][2], u);
        u = fmaf(Wi[8 + j][3], xx[k][3], u);
        float v = fmaf(Wh[8 + j][0], h[k][0], bnh[j]);
        v = fmaf(Wh[8 + j][1], h[k][1], v);
        v = fmaf(Wh[8 + j][2], h[k][2], v);
        v = fmaf(Wh[8 + j][3], h[k][3], v);
        y[k][j] = fmaf(sg[k][j], v, u) * (-2.0f * L2E);
      }
    float nn[2][4];
#pragma unroll
    for (int p = 0; p < 2; ++p)
#pragma unroll
      for (int k = 0; k < 2; ++k) {
        float f0 = fexp2(y[k][2 * p]);
        float f1 = fexp2(y[k][2 * p + 1]);
        float d0 = 1.0f + f0, d1 = 1.0f + f1;
        float R = frcp(d0 * d1);
        nn[k][2 * p] = fmaf(2.0f * d1, R, -1.0f);      // tanh = 2/(1+e^-2y) - 1
        nn[k][2 * p + 1] = fmaf(2.0f * d0, R, -1.0f);
      }
#pragma unroll
    for (int j = 0; j < 4; ++j)
#pragma unroll
      for (int k = 0; k < 2; ++k)
        h[k][j] = fmaf(sg[k][4 + j], h[k][j] - nn[k][j], nn[k][j]);
  };

  auto RUN4 = [&](float4 (&X)[2][4]) {
#pragma unroll
    for (int s = 0; s < 4; ++s) {
      float xx[2][4];
#pragma unroll
      for (int k = 0; k < 2; ++k)
#pragma unroll
        for (int c = 0; c < 4; ++c) xx[k][c] = f4c(X[k][c], s);
      STEPD(xx);
    }
  };

  auto EMIT4 = [&](float4 (&X)[2][4], int off) {
    float ob[2][4][4];
#pragma unroll
    for (int s = 0; s < 4; ++s) {
      float xx[2][4];
#pragma unroll
      for (int k = 0; k < 2; ++k)
#pragma unroll
        for (int c = 0; c < 4; ++c) xx[k][c] = f4c(X[k][c], s);
      STEPD(xx);
#pragma unroll
      for (int k = 0; k < 2; ++k)
#pragma unroll
        for (int c = 0; c < 4; ++c) ob[k][c][s] = h[k][c];
    }
#pragma unroll
    for (int k = 0; k < 2; ++k)
#pragma unroll
      for (int c = 0; c < 4; ++c)
        *(float4*)(po[k][c] + off) =
            make_float4(ob[k][c][0], ob[k][c][1], ob[k][c][2], ob[k][c][3]);
  };

  // Warm phase: double-buffered 4-step groups (trip count runtime -> body
  // stays resident in I-cache). nW4 is even.
  LDA(0);
  for (int g = 0; g < nW4; g += 2) {
    LDB((g + 1) * 4);
    RUN4(XA);
    LDA((g + 2) * 4);
    RUN4(XB);
  }
  // Emit phase: 4 groups; XA holds group nW4. Max load offset tw+60..63 < TT.
  LDB((nW4 + 1) * 4);
  EMIT4(XA, 0);
  LDA((nW4 + 2) * 4);
  EMIT4(XB, 4);
  LDB((nW4 + 3) * 4);
  EMIT4(XA, 8);
  EMIT4(XB, 12);
}

extern "C" void kernel_launch(void* const* d_in, const int* in_sizes, int n_in,
                              void* d_out, int out_size, void* d_ws, size_t ws_size,
                              hipStream_t stream) {
  const float* x   = (const float*)d_in[0];
  const float* wih = (const float*)d_in[1];
  const float* whh = (const float*)d_in[2];
  const float* bih = (const float*)d_in[3];
  const float* bhh = (const float*)d_in[4];
  float* out = (float*)d_out;

  gru_scan<<<dim3(TB / 128, NCH), 64, 0, stream>>>(x, wih, whh, bih, bhh, out);
}

// Round 6
// 148.579 us; speedup vs baseline: 1.5168x; 1.5168x over previous
//
#include <hip/hip_runtime.h>

// Batched tiny GRU: B=512, T=4096, C=hidden=4.
// R6 = R3's transposed-input coalesced loads + R5's 2-chains-per-lane ILP.
// R5 failed on memory: direct [b][c][t] strided loads with 8 streams/wave
// blew L1 (FETCH 35->432 MB). With xt[t][b*4+c] a step-load is 64 lanes x
// contiguous 16B = fully-consumed lines, ~2KB live footprint/wave.
// CHUNK=16, WARM=48 -> 131072 chains; 2 chains/lane -> 1024 waves = 1/SIMD.
// 18 trans-ops/step (paired rcp). Full-chunk output buffering -> one 64B
// line per (b,c,chunk), stores issued back-to-back (WRITE ~33 MB).

#define TB 512
#define TT 4096
#define CHUNK 16
#define WARM 48
#define NCH (TT / CHUNK)  // 256
#define L2E 1.4426950408889634f

__device__ __forceinline__ float fexp2(float x) { return __builtin_amdgcn_exp2f(x); }
__device__ __forceinline__ float frcp(float x)  { return __builtin_amdgcn_rcpf(x); }

// [2048][4096] -> [4096][2048] f32 transpose. 64x64 tiles, float4 global on
// both sides, stride-65 LDS (2-way bank aliasing only = free). Verified R2/R3.
__global__ __launch_bounds__(256) void transpose_k(const float* __restrict__ in,
                                                   float* __restrict__ out) {
  __shared__ float tile[64 * 65];
  const int tid = threadIdx.x;
  const int t0 = blockIdx.x * 64;
  const int r0 = blockIdx.y * 64;  // bc
  const float4* in4 = (const float4*)in;
  float4* out4 = (float4*)out;

  const int f4c = tid & 15;
  const int row = tid >> 4;
#pragma unroll
  for (int rr = 0; rr < 64; rr += 16) {
    float4 v = in4[(size_t)(r0 + row + rr) * (TT / 4) + (t0 >> 2) + f4c];
    const int tl = f4c * 4;
    const int bcl = row + rr;
    tile[(tl + 0) * 65 + bcl] = v.x;
    tile[(tl + 1) * 65 + bcl] = v.y;
    tile[(tl + 2) * 65 + bcl] = v.z;
    tile[(tl + 3) * 65 + bcl] = v.w;
  }
  __syncthreads();
  const int c2 = tid & 15;
  const int trw = tid >> 4;
#pragma unroll
  for (int rr = 0; rr < 64; rr += 16) {
    const int t = trw + rr;
    float4 v;
    v.x = tile[t * 65 + c2 * 4 + 0];
    v.y = tile[t * 65 + c2 * 4 + 1];
    v.z = tile[t * 65 + c2 * 4 + 2];
    v.w = tile[t * 65 + c2 * 4 + 3];
    out4[(size_t)(t0 + t) * (TB * 4 / 4) + (r0 >> 2) + c2] = v;
  }
}

__global__ __launch_bounds__(64, 1) void gru_scan(
    const float* __restrict__ xt, const float* __restrict__ wih,
    const float* __restrict__ whh, const float* __restrict__ bih,
    const float* __restrict__ bhh, float* __restrict__ out) {
  const int lane = threadIdx.x;
  const int ch = blockIdx.y;
  const int t0 = ch * CHUNK;
  const int tw = (t0 >= WARM) ? (t0 - WARM) : 0;
  const int nW4 = (t0 - tw) >> 2;  // warm 4-step groups: 0,4,8,12 (even)

  // Uniform weights/biases -> SGPRs.
  float Wi[12][4], Wh[12][4], bg[8], bnx[4], bnh[4];
#pragma unroll
  for (int g = 0; g < 12; ++g)
#pragma unroll
    for (int c = 0; c < 4; ++c) {
      Wi[g][c] = wih[g * 4 + c];
      Wh[g][c] = whh[g * 4 + c];
    }
#pragma unroll
  for (int g = 0; g < 8; ++g) bg[g] = bih[g] + bhh[g];
#pragma unroll
  for (int j = 0; j < 4; ++j) { bnx[j] = bih[8 + j]; bnh[j] = bhh[8 + j]; }

  const int bA = blockIdx.x * 128 + lane;  // chain 0; chain 1 = bA + 64
  // xt float4 index = t*512 + b : coalesced across lanes.
  const float4* xp = (const float4*)xt + (size_t)tw * TB + bA;

  float h[2][4] = {{0.f, 0.f, 0.f, 0.f}, {0.f, 0.f, 0.f, 0.f}};
  float4 XA[2][4], XB[2][4];  // [chain][step-in-group]

  auto LDA = [&](int g) {
#pragma unroll
    for (int s = 0; s < 4; ++s) {
      XA[0][s] = xp[(size_t)(g * 4 + s) * TB];
      XA[1][s] = xp[(size_t)(g * 4 + s) * TB + 64];
    }
  };
  auto LDB = [&](int g) {
#pragma unroll
    for (int s = 0; s < 4; ++s) {
      XB[0][s] = xp[(size_t)(g * 4 + s) * TB];
      XB[1][s] = xp[(size_t)(g * 4 + s) * TB + 64];
    }
  };

  // One GRU step for BOTH chains, stage-interleaved for ILP.
  auto STEPD = [&](float4 x0, float4 x1) {
    float xx[2][4] = {{x0.x, x0.y, x0.z, x0.w}, {x1.x, x1.y, x1.z, x1.w}};
    float ar[2][8];
#pragma unroll
    for (int g = 0; g < 8; ++g)
#pragma unroll
      for (int k = 0; k < 2; ++k) {
        float s = fmaf(Wi[g][0], xx[k][0], bg[g]);
        s = fmaf(Wi[g][1], xx[k][1], s);
        s = fmaf(Wi[g][2], xx[k][2], s);
        s = fmaf(Wi[g][3], xx[k][3], s);
        s = fmaf(Wh[g][0], h[k][0], s);
        s = fmaf(Wh[g][1], h[k][1], s);
        s = fmaf(Wh[g][2], h[k][2], s);
        ar[k][g] = fmaf(Wh[g][3], h[k][3], s);
      }
    float sg[2][8];
#pragma unroll
    for (int p = 0; p < 4; ++p)
#pragma unroll
      for (int k = 0; k < 2; ++k) {
        float e0 = fexp2(ar[k][2 * p] * -L2E);
        float e1 = fexp2(ar[k][2 * p + 1] * -L2E);
        float d0 = 1.0f + e0, d1 = 1.0f + e1;
        float R = frcp(d0 * d1);  // one rcp serves both sigmoids
        sg[k][2 * p] = d1 * R;
        sg[k][2 * p + 1] = d0 * R;
      }
    float y[2][4];
#pragma unroll
    for (int j = 0; j < 4; ++j)
#pragma unroll
      for (int k = 0; k < 2; ++k) {
        float u = fmaf(Wi[8 + j][0], xx[k][0], bnx[j]);
        u = fmaf(Wi[8 + j][1], xx[k][1], u);
        u = fmaf(Wi[8 + j][2], xx[k][2], u);
        u = fmaf(Wi[8 + j][3], xx[k][3], u);
        float v = fmaf(Wh[8 + j][0], h[k][0], bnh[j]);
        v = fmaf(Wh[8 + j][1], h[k][1], v);
        v = fmaf(Wh[8 + j][2], h[k][2], v);
        v = fmaf(Wh[8 + j][3], h[k][3], v);
        y[k][j] = fmaf(sg[k][j], v, u) * (-2.0f * L2E);
      }
    float nn[2][4];
#pragma unroll
    for (int p = 0; p < 2; ++p)
#pragma unroll
      for (int k = 0; k < 2; ++k) {
        float f0 = fexp2(y[k][2 * p]);
        float f1 = fexp2(y[k][2 * p + 1]);
        float d0 = 1.0f + f0, d1 = 1.0f + f1;
        float R = frcp(d0 * d1);
        nn[k][2 * p] = fmaf(2.0f * d1, R, -1.0f);  // tanh = 2/(1+e^-2y) - 1
        nn[k][2 * p + 1] = fmaf(2.0f * d0, R, -1.0f);
      }
#pragma unroll
    for (int j = 0; j < 4; ++j)
#pragma unroll
      for (int k = 0; k < 2; ++k)
        h[k][j] = fmaf(sg[k][4 + j], h[k][j] - nn[k][j], nn[k][j]);
  };

  float ob[2][4][16];  // full-chunk output buffer (one 64B line per (b,c))

  auto RUN4 = [&](float4 (&X)[2][4]) {
#pragma unroll
    for (int s = 0; s < 4; ++s) STEPD(X[0][s], X[1][s]);
  };
  auto EMIT4 = [&](float4 (&X)[2][4], int grp) {
#pragma unroll
    for (int s = 0; s < 4; ++s) {
      STEPD(X[0][s], X[1][s]);
#pragma unroll
      for (int k = 0; k < 2; ++k)
#pragma unroll
        for (int c = 0; c < 4; ++c) ob[k][c][grp * 4 + s] = h[k][c];
    }
  };

  // Warm phase: double-buffered 4-step groups; nW4 even; runtime trip count
  // keeps the hot body I-cache resident.
  LDA(0);
  for (int g = 0; g < nW4; g += 2) {
    LDB(g + 1);
    RUN4(XA);
    LDA(g + 2);
    RUN4(XB);
  }
  // Emit phase: groups nW4..nW4+3 (XA holds group nW4).
  // Max load t = tw + (nW4+3)*4 + 3 = t0 + 15 <= 4095: in-bounds, no clamp.
  LDB(nW4 + 1);
  EMIT4(XA, 0);
  LDA(nW4 + 2);
  EMIT4(XB, 1);
  LDB(nW4 + 3);
  EMIT4(XA, 2);
  EMIT4(XB, 3);

  // Flush: per (chain, channel) one 64B line as 4 consecutive float4 stores.
#pragma unroll
  for (int k = 0; k < 2; ++k)
#pragma unroll
    for (int c = 0; c < 4; ++c) {
      float4* op = (float4*)(out + ((size_t)(bA + 64 * k) * 4 + c) * TT + t0);
#pragma unroll
      for (int q = 0; q < 4; ++q)
        op[q] = make_float4(ob[k][c][q * 4 + 0], ob[k][c][q * 4 + 1],
                            ob[k][c][q * 4 + 2], ob[k][c][q * 4 + 3]);
    }
}

extern "C" void kernel_launch(void* const* d_in, const int* in_sizes, int n_in,
                              void* d_out, int out_size, void* d_ws, size_t ws_size,
                              hipStream_t stream) {
  const float* x   = (const float*)d_in[0];
  const float* wih = (const float*)d_in[1];
  const float* whh = (const float*)d_in[2];
  const float* bih = (const float*)d_in[3];
  const float* bhh = (const float*)d_in[4];
  float* out = (float*)d_out;
  float* xtr = (float*)d_ws;  // 32 MiB scratch

  transpose_k<<<dim3(TT / 64, (TB * 4) / 64), 256, 0, stream>>>(x, xtr);
  gru_scan<<<dim3(TB / 128, NCH), 64, 0, stream>>>(xtr, wih, whh, bih, bhh, out);
}